// Round 2
// baseline (21357.356 us; speedup 1.0000x reference)
//
#include <hip/hip_runtime.h>

#define BB 128
#define TT 1024
#define DD 512
#define HH 1024
#define NBLK 256
#define NTHR 384
#define KI 48            // K iters: 32 over h (K=1024), 16 over x (K=512)
#define AST 1536         // LDS A-row stride (bf16 elems); XOR chunk swizzle for banks
#define TST 17           // C-tile row stride (floats)
#define TSLOT 272        // 16 * TST floats per tile slot

typedef __attribute__((ext_vector_type(8))) short short8;
typedef __attribute__((ext_vector_type(4))) float float4v;
typedef unsigned long long u64;

__device__ __forceinline__ short f2bf(float f) {
    __bf16 b = (__bf16)f;
    return __builtin_bit_cast(short, b);
}
__device__ __forceinline__ float bf2f(unsigned short s) {
    union { unsigned int i; float f; } u; u.i = ((unsigned int)s) << 16; return u.f;
}
__device__ __forceinline__ float fast_tanh(float v) {
    v = fminf(15.f, fmaxf(-15.f, v));
    float e = __expf(2.f * v);
    return (e - 1.f) / (e + 1.f);
}

// ---- agent-scope primitives ----
__device__ __forceinline__ void memwait() {
    asm volatile("s_waitcnt vmcnt(0)" ::: "memory");
}
__device__ __forceinline__ int aload(int* p) {
    return __hip_atomic_load(p, __ATOMIC_RELAXED, __HIP_MEMORY_SCOPE_AGENT);
}
__device__ __forceinline__ void astore(int* p, int v) {
    __hip_atomic_store(p, v, __ATOMIC_RELAXED, __HIP_MEMORY_SCOPE_AGENT);
}
__device__ __forceinline__ void astore64(u64* p, u64 v) {
    __hip_atomic_store(p, v, __ATOMIC_RELAXED, __HIP_MEMORY_SCOPE_AGENT);
}

// x fp32 -> bf16 pre-convert (time-parallel, once per call).
__global__ void xcvt(const float* __restrict__ x, unsigned short* __restrict__ xb) {
    const size_t i = ((size_t)blockIdx.x * blockDim.x + threadIdx.x) * 8;
    float4 f0 = *(const float4*)(x + i);
    float4 f1 = *(const float4*)(x + i + 4);
    short8 b;
    b[0] = f2bf(f0.x); b[1] = f2bf(f0.y); b[2] = f2bf(f0.z); b[3] = f2bf(f0.w);
    b[4] = f2bf(f1.x); b[5] = f2bf(f1.y); b[6] = f2bf(f1.z); b[7] = f2bf(f1.w);
    *(short8*)((unsigned short*)xb + i) = b;
}

// Persistent MFMA GRU, dataflow sync (no grid barrier).
// 256 blocks (1/CU), 384 thr = 6 waves. Wave: mt = w&1, gate = w>>1.
// Batch groups grp = blockIdx&3 are fully independent; 64 producer flags per
// group + double-buffered h give exactly the needed ordering (see poll).
//
// h exchange protocol (this round's change):
//   producer: ATOMIC agent-scope 8B stores (bypass L1/L2 -> coherence point;
//             never creates dirty L2 lines anywhere) -> vmcnt(0) -> flag store.
//   consumer: poll flag (atomic) -> agent ACQUIRE fence (buffer_inv: drops
//             clean-but-stale L1/L2 copies) -> NORMAL CACHED 16B loads.
//   => each XCD's L2 fetches the group's 64KB slice once per step in 128B
//   lines; sibling blocks hit L2 instead of issuing 8192 bypass atomics each.
//   Freshness: lines are only fetched after flag>=t observed, i.e. after the
//   producers' stores reached the coherence point; the fence killed every
//   older cached copy. Group h ranges are 2KB-row disjoint (no line sharing).
template <bool XBF>
__global__ __launch_bounds__(NTHR, 2) void gru_mfma(
    const void* __restrict__ xsrc, const float* __restrict__ w_ih,
    const float* __restrict__ w_hh, const float* __restrict__ bias,
    const float* __restrict__ bn,
    unsigned short* __restrict__ h0, unsigned short* __restrict__ h1,
    int* __restrict__ flags)
{
    __shared__ __align__(16) unsigned short smem[32 * AST];  // 98304 B
    float* tiles = (float*)smem;  // epilogue alias (first ~8.7 KB), after sync

    const int tid  = threadIdx.x;
    const int wave = tid >> 6;
    const int lane = tid & 63;
    const int mt   = wave & 1;
    const int gate = wave >> 1;
    const int jg   = blockIdx.x >> 2;
    const int grp  = blockIdx.x & 3;
    const int m0   = grp * 32;
    const int ln   = lane & 15;
    const int q    = lane >> 4;

    int* myflag = flags + (grp << 6) + jg;
    int* pollflag = flags + (grp << 6) + (tid & 63);  // valid for tid<64

    // ---- B fragments (weights), loaded once ----
    const int nrow = gate * HH + jg * 16 + ln;
    const float* whh_row = w_hh + (size_t)nrow * HH;
    const float* wih_row = w_ih + (size_t)nrow * DD;
    short8 Bfrag[KI];
    #pragma unroll
    for (int i = 0; i < KI; ++i) {
        const float* src = (i < 32) ? (whh_row + i * 32 + q * 8)
                                    : (wih_row + (i - 32) * 32 + q * 8);
        float4 f0 = *(const float4*)src;
        float4 f1 = *(const float4*)(src + 4);
        short8 b;
        b[0] = f2bf(f0.x); b[1] = f2bf(f0.y); b[2] = f2bf(f0.z); b[3] = f2bf(f0.w);
        b[4] = f2bf(f1.x); b[5] = f2bf(f1.y); b[6] = f2bf(f1.z); b[7] = f2bf(f1.w);
        Bfrag[i] = b;
    }

    // ---- epilogue constants hoisted (waves 0-1 only; wave-uniform branch) ----
    float ebr[4], ebz[4], eb2[4], ebn[4];
    int em = 0, ej0 = 0;
    if (tid < 128) {
        em = tid >> 2; ej0 = (tid & 3) * 4;
        #pragma unroll
        for (int u = 0; u < 4; ++u) {
            int jgl = jg * 16 + ej0 + u;
            ebr[u] = bias[jgl];
            ebz[u] = bias[HH + jgl];
            eb2[u] = bias[2 * HH + jgl];
            ebn[u] = bn[jgl];
        }
    }

    const int arow = mt * 16 + ln;
    const int asw  = arow & 7;

    for (int t = 0; t < TT; ++t) {
        const unsigned short* hin  = (t & 1) ? h1 : h0;
        unsigned short*       hout = (t & 1) ? h0 : h1;

        // ---- wave 0: poll group flags for h_t ready; waves 1-5: stage x_t ----
        if (tid < 64) {
            while (aload(pollflag) < t) __builtin_amdgcn_s_sleep(1);
        } else {
            const int tx = tid - 64;  // 0..319
            for (int c = tx; c < 2048; c += NTHR - 64) {
                int r = c >> 6, cx = c & 63;
                int chunk = (128 + cx) ^ (r & 7);
                if (XBF) {
                    const unsigned short* xb = (const unsigned short*)xsrc;
                    int4 v = *(const int4*)(xb + (size_t)(m0 + r) * TT * DD + (size_t)t * DD + cx * 8);
                    *(int4*)&smem[r * AST + chunk * 8] = v;
                } else {
                    const float* xf = (const float*)xsrc;
                    const float* src = xf + (size_t)(m0 + r) * TT * DD + (size_t)t * DD + cx * 8;
                    float4 f0 = *(const float4*)src;
                    float4 f1 = *(const float4*)(src + 4);
                    short8 b;
                    b[0] = f2bf(f0.x); b[1] = f2bf(f0.y); b[2] = f2bf(f0.z); b[3] = f2bf(f0.w);
                    b[4] = f2bf(f1.x); b[5] = f2bf(f1.y); b[6] = f2bf(f1.z); b[7] = f2bf(f1.w);
                    *(short8*)&smem[r * AST + chunk * 8] = b;
                }
            }
        }
        __syncthreads();
        // Acquire at agent scope: emits buffer_inv -> drops stale clean h
        // lines from this CU's L1 and the XCD's L2; orders the h loads below.
        __builtin_amdgcn_fence(__ATOMIC_ACQUIRE, "agent");

        // ---- stage h rows -> LDS (NORMAL cached 16B loads, swizzled) ----
        for (int c = tid; c < 4096; c += NTHR) {
            int r = c >> 7, cc16 = c & 127;                   // 128 x 16B per row
            int4 v = *(const int4*)(hin + (size_t)(m0 + r) * HH + cc16 * 8);
            int chunk = cc16 ^ (r & 7);
            *(int4*)&smem[r * AST + chunk * 8] = v;
        }
        __syncthreads();

        // ---- K-loop ----
        float4v accA = {0.f, 0.f, 0.f, 0.f};
        float4v accB = {0.f, 0.f, 0.f, 0.f};
        #pragma unroll
        for (int i = 0; i < 32; ++i) {
            short8 a = *(const short8*)&smem[arow * AST + (((i * 4 + q) ^ asw) * 8)];
            accA = __builtin_amdgcn_mfma_f32_16x16x32_bf16(a, Bfrag[i], accA, 0, 0, 0);
        }
        #pragma unroll
        for (int i = 32; i < KI; ++i) {
            short8 a = *(const short8*)&smem[arow * AST + (((i * 4 + q) ^ asw) * 8)];
            accB = __builtin_amdgcn_mfma_f32_16x16x32_bf16(a, Bfrag[i], accB, 0, 0, 0);
        }

        // ---- pre-read h_prev (LDS h area, before tiles alias overwrite) ----
        float hp4[4];
        if (tid < 128) {
            int cj = jg * 16 + ej0;
            int chunk = (cj >> 3) ^ (em & 7);
            const unsigned short* p = &smem[em * AST + chunk * 8 + (cj & 7)];
            hp4[0] = bf2f(p[0]); hp4[1] = bf2f(p[1]);
            hp4[2] = bf2f(p[2]); hp4[3] = bf2f(p[3]);
        }
        __syncthreads();  // all smem reads done before tiles alias write

        // ---- C tiles -> LDS: slots 0=r, 1=z, 2=hg_n, 3=ig_n ----
        if (gate == 2) {
            float* tA = tiles + (mt * 4 + 2) * TSLOT;
            float* tB = tiles + (mt * 4 + 3) * TSLOT;
            #pragma unroll
            for (int r = 0; r < 4; ++r) {
                tA[(q * 4 + r) * TST + ln] = accA[r];
                tB[(q * 4 + r) * TST + ln] = accB[r];
            }
        } else {
            float* tA = tiles + (mt * 4 + gate) * TSLOT;
            #pragma unroll
            for (int r = 0; r < 4; ++r)
                tA[(q * 4 + r) * TST + ln] = accA[r] + accB[r];
        }
        __syncthreads();

        // ---- epilogue: waves 0-1, 4 consecutive j per thread, packed 8B store ----
        if (tid < 128) {
            const float* base = tiles + (em >> 4) * (4 * TSLOT) + (em & 15) * TST + ej0;
            u64 pk = 0;
            #pragma unroll
            for (int u = 0; u < 4; ++u) {
                float cr = base[u], cz = base[TSLOT + u], chn = base[2 * TSLOT + u], cin = base[3 * TSLOT + u];
                float rr = 1.f / (1.f + __expf(-(cr + ebr[u])));
                float zz = 1.f / (1.f + __expf(-(cz + ebz[u])));
                float nn = fast_tanh(cin + eb2[u] + rr * (chn + ebn[u]));
                float hv = nn + zz * (hp4[u] - nn);
                pk |= ((u64)(unsigned short)f2bf(hv)) << (16 * u);
            }
            astore64((u64*)&hout[(size_t)(m0 + em) * HH + jg * 16 + ej0], pk);
            memwait();  // drain this wave's h stores before flag release
        }
        __syncthreads();  // both epilogue waves drained
        if (tid == 0) astore(myflag, t + 1);
    }
}

// out[b] = h_final[b,:] . w_out + b_out  (h_final bf16 in h0)
__global__ void gru_out(const unsigned short* __restrict__ h,
                        const float* __restrict__ w_out,
                        const float* __restrict__ b_out, float* __restrict__ out)
{
    __shared__ float red[4];
    const int b = blockIdx.x, tid = threadIdx.x;
    const int col = tid * 4;
    ushort4 hv = *(const ushort4*)(h + (size_t)b * HH + col);
    float4  wv = *(const float4*)(w_out + col);
    float s = bf2f(hv.x) * wv.x + bf2f(hv.y) * wv.y + bf2f(hv.z) * wv.z + bf2f(hv.w) * wv.w;
    #pragma unroll
    for (int off = 32; off > 0; off >>= 1) s += __shfl_down(s, off, 64);
    if ((tid & 63) == 0) red[tid >> 6] = s;
    __syncthreads();
    if (tid == 0) out[b] = red[0] + red[1] + red[2] + red[3] + b_out[0];
}

extern "C" void kernel_launch(void* const* d_in, const int* in_sizes, int n_in,
                              void* d_out, int out_size, void* d_ws, size_t ws_size,
                              hipStream_t stream) {
    const float* x     = (const float*)d_in[0];
    const float* w_ih  = (const float*)d_in[1];
    const float* w_hh  = (const float*)d_in[2];
    const float* bias  = (const float*)d_in[3];
    const float* bn    = (const float*)d_in[4];
    const float* w_out = (const float*)d_in[5];
    const float* b_out = (const float*)d_in[6];

    const size_t xbytes = (size_t)BB * TT * DD * 2;          // 128 MB bf16 x
    const size_t hbytes = (size_t)BB * HH * 2;               // 256 KB per h buffer
    const bool use_xbf = ws_size >= xbytes + 2 * hbytes + 8192;

    char* base = (char*)d_ws;
    unsigned short* xb = (unsigned short*)base;
    char* hb = use_xbf ? base + xbytes : base;
    unsigned short* h0 = (unsigned short*)hb;
    unsigned short* h1 = (unsigned short*)(hb + hbytes);
    int* flags = (int*)(hb + 2 * hbytes);

    // ws re-poisoned 0xAA each call: re-init h0 and flag lines every call.
    hipMemsetAsync(h0, 0, hbytes, stream);
    hipMemsetAsync(flags, 0, 8192, stream);

    if (use_xbf) {
        xcvt<<<(BB * TT * DD / 8 + 255) / 256, 256, 0, stream>>>(x, xb);
        gru_mfma<true><<<NBLK, NTHR, 0, stream>>>(xb, w_ih, w_hh, bias, bn, h0, h1, flags);
    } else {
        gru_mfma<false><<<NBLK, NTHR, 0, stream>>>(x, w_ih, w_hh, bias, bn, h0, h1, flags);
    }
    gru_out<<<BB, 256, 0, stream>>>(h0, w_out, b_out, (float*)d_out);
}

// Round 3
// 11935.794 us; speedup vs baseline: 1.7894x; 1.7894x over previous
//
#include <hip/hip_runtime.h>

#define BB 128
#define TT 1024
#define DD 512
#define HH 1024
#define NBLK 256
#define NTHR 384
#define KI 48            // K iters: 32 over h (K=1024), 16 over x (K=512)
#define MROWS 16         // batch rows per group/block
#define AST 1536         // LDS A-row stride (bf16 elems); XOR chunk swizzle for banks
#define TST 17           // C-tile row stride (floats)
#define TSLOT 272        // 16 * TST floats per tile slot

typedef __attribute__((ext_vector_type(8))) short short8;
typedef __attribute__((ext_vector_type(4))) float float4v;
typedef unsigned long long u64;

__device__ __forceinline__ short f2bf(float f) {
    __bf16 b = (__bf16)f;
    return __builtin_bit_cast(short, b);
}
__device__ __forceinline__ float bf2f(unsigned short s) {
    union { unsigned int i; float f; } u; u.i = ((unsigned int)s) << 16; return u.f;
}
__device__ __forceinline__ float fast_tanh(float v) {
    v = fminf(15.f, fmaxf(-15.f, v));
    float e = __expf(2.f * v);
    return (e - 1.f) / (e + 1.f);
}

// ---- agent-scope primitives (MALL-direct; no fences anywhere) ----
__device__ __forceinline__ void memwait() {
    asm volatile("s_waitcnt vmcnt(0)" ::: "memory");
}
__device__ __forceinline__ int aload(int* p) {
    return __hip_atomic_load(p, __ATOMIC_RELAXED, __HIP_MEMORY_SCOPE_AGENT);
}
__device__ __forceinline__ void astore(int* p, int v) {
    __hip_atomic_store(p, v, __ATOMIC_RELAXED, __HIP_MEMORY_SCOPE_AGENT);
}
__device__ __forceinline__ void astore64(u64* p, u64 v) {
    __hip_atomic_store(p, v, __ATOMIC_RELAXED, __HIP_MEMORY_SCOPE_AGENT);
}

// x fp32 -> bf16 pre-convert (time-parallel, once per call).
__global__ void xcvt(const float* __restrict__ x, unsigned short* __restrict__ xb) {
    const size_t i = ((size_t)blockIdx.x * blockDim.x + threadIdx.x) * 8;
    float4 f0 = *(const float4*)(x + i);
    float4 f1 = *(const float4*)(x + i + 4);
    short8 b;
    b[0] = f2bf(f0.x); b[1] = f2bf(f0.y); b[2] = f2bf(f0.z); b[3] = f2bf(f0.w);
    b[4] = f2bf(f1.x); b[5] = f2bf(f1.y); b[6] = f2bf(f1.z); b[7] = f2bf(f1.w);
    *(short8*)((unsigned short*)xb + i) = b;
}

// Persistent MFMA GRU, dataflow sync (no grid barrier, no cache fences).
// 256 blocks (1/CU), 384 thr = 6 waves. 8 batch-groups (grp=blockIdx&7, 16
// rows each) x 32 col-blocks (jg=blockIdx>>3, 32 cols/gate each).
// Wave w: gate = w>>1, ch = w&1 -> one 16x16 col-tile (cols jg*32+ch*16..+15).
//
// h exchange protocol (round-1 protocol, transactions quartered):
//   producer: agent-scope 8B atomic stores (MALL-direct; never creates dirty
//             cached lines) -> vmcnt(0) -> flag store (agent atomic).
//   consumer: poll group's 32 flags >= t (agent atomic loads) ->
//             16B `global_load_dwordx4 ... sc1` batched 6-deep per thread
//             (device-scope cache-bypass reads; atomicity unneeded: data is
//             flag-guarded and stable; same MALL path the atomics use).
//   Per step: 256 blocks x 16 rows x 2KB = 8MB read as 0.52M 16B transactions
//   (was 16MB as 2.1M 8B) -- the MALL transaction rate was the binder.
template <bool XBF>
__global__ __launch_bounds__(NTHR, 2) void gru_mfma(
    const void* __restrict__ xsrc, const float* __restrict__ w_ih,
    const float* __restrict__ w_hh, const float* __restrict__ bias,
    const float* __restrict__ bn,
    unsigned short* __restrict__ h0, unsigned short* __restrict__ h1,
    int* __restrict__ flags)
{
    __shared__ __align__(16) unsigned short smem[MROWS * AST];  // 49152 B
    float* tiles = (float*)smem;  // epilogue alias (first ~8.7 KB), after sync

    const int tid  = threadIdx.x;
    const int wave = tid >> 6;
    const int lane = tid & 63;
    const int gate = wave >> 1;
    const int ch   = wave & 1;
    const int jg   = blockIdx.x >> 3;   // 0..31
    const int grp  = blockIdx.x & 7;    // 0..7
    const int m0   = grp * MROWS;
    const int ln   = lane & 15;
    const int q    = lane >> 4;

    int* myflag   = flags + (grp << 5) + jg;
    int* pollflag = flags + (grp << 5) + (lane & 31);  // valid for tid<64

    // ---- B fragments (weights), loaded once: rows = 16 cols of this tile ----
    const int nrow = gate * HH + jg * 32 + ch * 16 + ln;
    const float* whh_row = w_hh + (size_t)nrow * HH;
    const float* wih_row = w_ih + (size_t)nrow * DD;
    short8 Bfrag[KI];
    #pragma unroll
    for (int i = 0; i < KI; ++i) {
        const float* src = (i < 32) ? (whh_row + i * 32 + q * 8)
                                    : (wih_row + (i - 32) * 32 + q * 8);
        float4 f0 = *(const float4*)src;
        float4 f1 = *(const float4*)(src + 4);
        short8 b;
        b[0] = f2bf(f0.x); b[1] = f2bf(f0.y); b[2] = f2bf(f0.z); b[3] = f2bf(f0.w);
        b[4] = f2bf(f1.x); b[5] = f2bf(f1.y); b[6] = f2bf(f1.z); b[7] = f2bf(f1.w);
        Bfrag[i] = b;
    }

    // ---- epilogue constants (waves 0-1; thread -> (row em, 4 cols at ej0)) ----
    float ebr[4], ebz[4], eb2[4], ebn[4];
    int em = 0, ej0 = 0;
    if (tid < 128) {
        em = tid >> 3; ej0 = (tid & 7) * 4;   // em 0..15, ej0 0..28
        #pragma unroll
        for (int u = 0; u < 4; ++u) {
            int jgl = jg * 32 + ej0 + u;
            ebr[u] = bias[jgl];
            ebz[u] = bias[HH + jgl];
            eb2[u] = bias[2 * HH + jgl];
            ebn[u] = bn[jgl];
        }
    }

    const int asw = ln & 7;

    for (int t = 0; t < TT; ++t) {
        const unsigned short* hin  = (t & 1) ? h1 : h0;
        unsigned short*       hout = (t & 1) ? h0 : h1;

        // ---- wave 0: poll group flags for h_t ready; waves 1-5: stage x_t ----
        if (tid < 64) {
            while (aload(pollflag) < t) __builtin_amdgcn_s_sleep(1);
        } else {
            const int tx = tid - 64;  // 0..319
            for (int c = tx; c < 1024; c += NTHR - 64) {
                int r = c >> 6, cx = c & 63;
                int chunk = (128 + cx) ^ (r & 7);
                if (XBF) {
                    const unsigned short* xb = (const unsigned short*)xsrc;
                    int4 v = *(const int4*)(xb + (size_t)(m0 + r) * TT * DD + (size_t)t * DD + cx * 8);
                    *(int4*)&smem[r * AST + chunk * 8] = v;
                } else {
                    const float* xf = (const float*)xsrc;
                    const float* src = xf + (size_t)(m0 + r) * TT * DD + (size_t)t * DD + cx * 8;
                    float4 f0 = *(const float4*)src;
                    float4 f1 = *(const float4*)(src + 4);
                    short8 b;
                    b[0] = f2bf(f0.x); b[1] = f2bf(f0.y); b[2] = f2bf(f0.z); b[3] = f2bf(f0.w);
                    b[4] = f2bf(f1.x); b[5] = f2bf(f1.y); b[6] = f2bf(f1.z); b[7] = f2bf(f1.w);
                    *(short8*)&smem[r * AST + chunk * 8] = b;
                }
            }
        }
        __syncthreads();
        asm volatile("" ::: "memory");  // h loads must not hoist above the poll

        // ---- stage h rows -> LDS: 16B sc1 (MALL-direct) loads, 6-deep ----
        // 2048 16B chunks; 6 per thread with &2047 wrap (duplicate loads write
        // identical values to identical LDS slots -- benign).
        if (t > 0) {
            const unsigned short* hbase = hin + (size_t)m0 * HH;
            const unsigned short* ga[6];
            int la[6];
            #pragma unroll
            for (int k = 0; k < 6; ++k) {
                int c = (tid + k * NTHR) & 2047;
                int r = c >> 7, cc16 = c & 127;
                ga[k] = hbase + r * HH + cc16 * 8;
                la[k] = r * AST + (cc16 ^ (r & 7)) * 8;
            }
            int4 v0, v1, v2, v3, v4, v5;
            asm volatile(
                "global_load_dwordx4 %0, %6, off sc1\n\t"
                "global_load_dwordx4 %1, %7, off sc1\n\t"
                "global_load_dwordx4 %2, %8, off sc1\n\t"
                "global_load_dwordx4 %3, %9, off sc1\n\t"
                "global_load_dwordx4 %4, %10, off sc1\n\t"
                "global_load_dwordx4 %5, %11, off sc1\n\t"
                "s_waitcnt vmcnt(0)"
                : "=&v"(v0), "=&v"(v1), "=&v"(v2), "=&v"(v3), "=&v"(v4), "=&v"(v5)
                : "v"(ga[0]), "v"(ga[1]), "v"(ga[2]), "v"(ga[3]), "v"(ga[4]), "v"(ga[5])
                : "memory");
            *(int4*)&smem[la[0]] = v0;
            *(int4*)&smem[la[1]] = v1;
            *(int4*)&smem[la[2]] = v2;
            *(int4*)&smem[la[3]] = v3;
            *(int4*)&smem[la[4]] = v4;
            *(int4*)&smem[la[5]] = v5;
        }
        __syncthreads();

        // ---- K-loop: wave computes one 16x16 tile; h part (accA) + x part (accB) ----
        float4v accA = {0.f, 0.f, 0.f, 0.f};
        float4v accB = {0.f, 0.f, 0.f, 0.f};
        if (t > 0) {
            #pragma unroll
            for (int i = 0; i < 32; ++i) {
                short8 a = *(const short8*)&smem[ln * AST + (((i * 4 + q) ^ asw) * 8)];
                accA = __builtin_amdgcn_mfma_f32_16x16x32_bf16(a, Bfrag[i], accA, 0, 0, 0);
            }
        }
        #pragma unroll
        for (int i = 32; i < KI; ++i) {
            short8 a = *(const short8*)&smem[ln * AST + (((i * 4 + q) ^ asw) * 8)];
            accB = __builtin_amdgcn_mfma_f32_16x16x32_bf16(a, Bfrag[i], accB, 0, 0, 0);
        }

        // ---- pre-read h_prev (LDS h area, before tiles alias overwrite) ----
        float hp4[4] = {0.f, 0.f, 0.f, 0.f};
        if (tid < 128 && t > 0) {
            int cj = jg * 32 + ej0;
            int chunk = (cj >> 3) ^ (em & 7);
            const unsigned short* p = &smem[em * AST + chunk * 8 + (cj & 7)];
            hp4[0] = bf2f(p[0]); hp4[1] = bf2f(p[1]);
            hp4[2] = bf2f(p[2]); hp4[3] = bf2f(p[3]);
        }
        __syncthreads();  // all smem reads done before tiles alias write

        // ---- C tiles -> LDS: slots r:0,1 z:2,3 n_h:4,5 n_x:6,7 (per col-half) ----
        if (gate == 2) {
            float* tA = tiles + (4 + ch) * TSLOT;
            float* tB = tiles + (6 + ch) * TSLOT;
            #pragma unroll
            for (int r = 0; r < 4; ++r) {
                tA[(q * 4 + r) * TST + ln] = accA[r];
                tB[(q * 4 + r) * TST + ln] = accB[r];
            }
        } else {
            float* tA = tiles + (gate * 2 + ch) * TSLOT;
            #pragma unroll
            for (int r = 0; r < 4; ++r)
                tA[(q * 4 + r) * TST + ln] = accA[r] + accB[r];
        }
        __syncthreads();

        // ---- epilogue: waves 0-1, 4 consecutive j per thread, packed 8B store ----
        if (tid < 128) {
            const int ech = ej0 >> 4;     // which 16-col half
            const int ec  = ej0 & 15;
            const float* base = tiles + em * TST + ec;
            u64 pk = 0;
            #pragma unroll
            for (int u = 0; u < 4; ++u) {
                float cr  = base[(0 + ech) * TSLOT + u];
                float cz  = base[(2 + ech) * TSLOT + u];
                float chn = base[(4 + ech) * TSLOT + u];
                float cin = base[(6 + ech) * TSLOT + u];
                float rr = 1.f / (1.f + __expf(-(cr + ebr[u])));
                float zz = 1.f / (1.f + __expf(-(cz + ebz[u])));
                float nn = fast_tanh(cin + eb2[u] + rr * (chn + ebn[u]));
                float hv = nn + zz * (hp4[u] - nn);
                pk |= ((u64)(unsigned short)f2bf(hv)) << (16 * u);
            }
            astore64((u64*)&hout[(size_t)(m0 + em) * HH + jg * 32 + ej0], pk);
            memwait();  // drain this wave's h stores before flag release
        }
        __syncthreads();  // both epilogue waves drained
        if (tid == 0) astore(myflag, t + 1);
    }
}

// out[b] = h_final[b,:] . w_out + b_out  (h_final bf16 in h0)
__global__ void gru_out(const unsigned short* __restrict__ h,
                        const float* __restrict__ w_out,
                        const float* __restrict__ b_out, float* __restrict__ out)
{
    __shared__ float red[4];
    const int b = blockIdx.x, tid = threadIdx.x;
    const int col = tid * 4;
    ushort4 hv = *(const ushort4*)(h + (size_t)b * HH + col);
    float4  wv = *(const float4*)(w_out + col);
    float s = bf2f(hv.x) * wv.x + bf2f(hv.y) * wv.y + bf2f(hv.z) * wv.z + bf2f(hv.w) * wv.w;
    #pragma unroll
    for (int off = 32; off > 0; off >>= 1) s += __shfl_down(s, off, 64);
    if ((tid & 63) == 0) red[tid >> 6] = s;
    __syncthreads();
    if (tid == 0) out[b] = red[0] + red[1] + red[2] + red[3] + b_out[0];
}

extern "C" void kernel_launch(void* const* d_in, const int* in_sizes, int n_in,
                              void* d_out, int out_size, void* d_ws, size_t ws_size,
                              hipStream_t stream) {
    const float* x     = (const float*)d_in[0];
    const float* w_ih  = (const float*)d_in[1];
    const float* w_hh  = (const float*)d_in[2];
    const float* bias  = (const float*)d_in[3];
    const float* bn    = (const float*)d_in[4];
    const float* w_out = (const float*)d_in[5];
    const float* b_out = (const float*)d_in[6];

    const size_t xbytes = (size_t)BB * TT * DD * 2;          // 128 MB bf16 x
    const size_t hbytes = (size_t)BB * HH * 2;               // 256 KB per h buffer
    const bool use_xbf = ws_size >= xbytes + 2 * hbytes + 8192;

    char* base = (char*)d_ws;
    unsigned short* xb = (unsigned short*)base;
    char* hb = use_xbf ? base + xbytes : base;
    unsigned short* h0 = (unsigned short*)hb;
    unsigned short* h1 = (unsigned short*)(hb + hbytes);
    int* flags = (int*)(hb + 2 * hbytes);

    // ws re-poisoned 0xAA each call: flags must be re-zeroed (poison reads as
    // negative -> permanent poll). h buffers need no init: t=0 skips h reads.
    hipMemsetAsync(flags, 0, 8192, stream);

    if (use_xbf) {
        xcvt<<<(BB * TT * DD / 8 + 255) / 256, 256, 0, stream>>>(x, xb);
        gru_mfma<true><<<NBLK, NTHR, 0, stream>>>(xb, w_ih, w_hh, bias, bn, h0, h1, flags);
    } else {
        gru_mfma<false><<<NBLK, NTHR, 0, stream>>>(x, w_ih, w_hh, bias, bn, h0, h1, flags);
    }
    gru_out<<<BB, 256, 0, stream>>>(h0, w_out, b_out, (float*)d_out);
}